// Round 3
// baseline (181.145 us; speedup 1.0000x reference)
//
#include <hip/hip_runtime.h>

// HybridSymmetricLoss: B=65536, T=3, J=10 (fp32).
// C[tl][ta] = sum_jk BCE(assign[b,ta,jk], labels[b,tl,jk]);
// loss = min over 6 perms of mean C[t][perm[t]] + category BCE under argmin
// perm. Logs in log2 space (clip -100/ln2), scaled by ln2 once at the end.
//
// Mapping: one b per 32-lane half-wave, lanes 0..24 hold 4 jk via float4.
// Each half-wave processes ITERS=4 b's grid-stride with double-buffered
// prefetch (loads for b+1 overlap butterfly/epilogue of b).
// s1 folded into the 9 dot partials -> butterfly reduces 9 values, 5 stages.
// Two-pass final sum via d_ws.

#define CLIP2 (-144.26950408889634f)   // -100 / ln(2)
#define LN2   (0.6931471805599453f)

__device__ __forceinline__ void load_b(const float* __restrict__ assign,
                                       const float* __restrict__ assign_lab,
                                       const float* __restrict__ cat,
                                       const float* __restrict__ cat_lab,
                                       int b, bool act, int o, int sub,
                                       float4 (&A)[3], float4 (&Y)[3],
                                       float (&cb)[3], float (&gb)[3]) {
    if (act) {
        const float* Ab = assign     + (size_t)b * 300 + o;
        const float* Yb = assign_lab + (size_t)b * 300 + o;
        A[0] = *(const float4*)(Ab);
        A[1] = *(const float4*)(Ab + 100);
        A[2] = *(const float4*)(Ab + 200);
        Y[0] = *(const float4*)(Yb);
        Y[1] = *(const float4*)(Yb + 100);
        Y[2] = *(const float4*)(Yb + 200);
    }
    if (sub == 0) {
        const float* cp = cat     + (size_t)b * 3;
        const float* gp = cat_lab + (size_t)b * 3;
        cb[0] = cp[0]; cb[1] = cp[1]; cb[2] = cp[2];
        gb[0] = gp[0]; gb[1] = gp[1]; gb[2] = gp[2];
    }
}

__device__ __forceinline__ void compute_b(bool act, int sub,
                                          const float4 (&A)[3],
                                          const float4 (&Y)[3],
                                          const float (&cb)[3],
                                          const float (&gb)[3],
                                          float& lsum) {
    float e[3][3] = {{0.f,0.f,0.f},{0.f,0.f,0.f},{0.f,0.f,0.f}};

    if (act) {
        float a[3][4] = {{A[0].x,A[0].y,A[0].z,A[0].w},
                         {A[1].x,A[1].y,A[1].z,A[1].w},
                         {A[2].x,A[2].y,A[2].z,A[2].w}};
        float y[3][4] = {{Y[0].x,Y[0].y,Y[0].z,Y[0].w},
                         {Y[1].x,Y[1].y,Y[1].z,Y[1].w},
                         {Y[2].x,Y[2].y,Y[2].z,Y[2].w}};
        float d[3][4];
        float s1p[3] = {0.f, 0.f, 0.f};
        #pragma unroll
        for (int t = 0; t < 3; ++t) {
            #pragma unroll
            for (int c = 0; c < 4; ++c) {
                float lp = fmaxf(__log2f(a[t][c]),       CLIP2);
                float l1 = fmaxf(__log2f(1.0f - a[t][c]), CLIP2);
                d[t][c] = lp - l1;
                s1p[t] += l1;
            }
        }
        #pragma unroll
        for (int tl = 0; tl < 3; ++tl) {
            #pragma unroll
            for (int ta = 0; ta < 3; ++ta) {
                float acc = s1p[ta];
                #pragma unroll
                for (int c = 0; c < 4; ++c)
                    acc = fmaf(y[tl][c], d[ta][c], acc);
                e[tl][ta] = acc;
            }
        }
    }

    // 5-stage butterfly within each 32-lane half (both halves in parallel)
    #pragma unroll
    for (int off = 16; off > 0; off >>= 1) {
        #pragma unroll
        for (int tl = 0; tl < 3; ++tl)
            #pragma unroll
            for (int ta = 0; ta < 3; ++ta)
                e[tl][ta] += __shfl_xor(e[tl][ta], off, 64);
    }

    if (sub == 0) {
        // Cm[tl][ta] = -E[tl][ta]; min over perms of sum Cm = -(max sum E)
        const int P0[6] = {0,0,1,1,2,2};
        const int P1[6] = {1,2,0,2,0,1};
        const int P2[6] = {2,1,2,0,1,0};
        float best = e[0][0] + e[1][1] + e[2][2];
        int bp0 = 0, bp1 = 1, bp2 = 2;
        #pragma unroll
        for (int p = 1; p < 6; ++p) {
            float l = e[0][P0[p]] + e[1][P1[p]] + e[2][P2[p]];
            if (l > best) { best = l; bp0 = P0[p]; bp1 = P1[p]; bp2 = P2[p]; }
        }

        float lp0 = fmaxf(__log2f(cb[0]), CLIP2), l10 = fmaxf(__log2f(1.f-cb[0]), CLIP2);
        float lp1 = fmaxf(__log2f(cb[1]), CLIP2), l11 = fmaxf(__log2f(1.f-cb[1]), CLIP2);
        float lp2 = fmaxf(__log2f(cb[2]), CLIP2), l12 = fmaxf(__log2f(1.f-cb[2]), CLIP2);

        float lpa = (bp0==0)?lp0:((bp0==1)?lp1:lp2);
        float l1a = (bp0==0)?l10:((bp0==1)?l11:l12);
        float lpb = (bp1==0)?lp0:((bp1==1)?lp1:lp2);
        float l1b = (bp1==0)?l10:((bp1==1)?l11:l12);
        float lpc = (bp2==0)?lp0:((bp2==1)?lp1:lp2);
        float l1c = (bp2==0)?l10:((bp2==1)?l11:l12);

        float csum = -(gb[0]*lpa + (1.f-gb[0])*l1a
                     + gb[1]*lpb + (1.f-gb[1])*l1b
                     + gb[2]*lpc + (1.f-gb[2])*l1c);

        lsum += best * (-1.f/300.f) + csum * (1.f/3.f);
    }
}

__launch_bounds__(256)
__global__ void hybrid_pass1(const float* __restrict__ assign,
                             const float* __restrict__ cat,
                             const float* __restrict__ assign_lab,
                             const float* __restrict__ cat_lab,
                             float* __restrict__ ws, int B) {
    const int sub = threadIdx.x & 31;
    const int hid = (blockIdx.x * blockDim.x + threadIdx.x) >> 5;
    const int nh  = (gridDim.x * blockDim.x) >> 5;
    const bool act = sub < 25;
    const int o = sub * 4;

    float4 A0[3], Y0[3], A1[3], Y1[3];
    float  c0[3], g0[3], c1[3], g1[3];
    float  lsum = 0.f;

    int b = hid;
    if (b < B) {
        load_b(assign, assign_lab, cat, cat_lab, b, act, o, sub, A0, Y0, c0, g0);
        while (true) {
            int b1 = b + nh;
            if (b1 < B)
                load_b(assign, assign_lab, cat, cat_lab, b1, act, o, sub, A1, Y1, c1, g1);
            compute_b(act, sub, A0, Y0, c0, g0, lsum);
            if (b1 >= B) break;
            int b2 = b1 + nh;
            if (b2 < B)
                load_b(assign, assign_lab, cat, cat_lab, b2, act, o, sub, A0, Y0, c0, g0);
            compute_b(act, sub, A1, Y1, c1, g1, lsum);
            if (b2 >= B) break;
            b = b2;
        }
    }

    float local = (sub == 0) ? lsum * (LN2 / 65536.f) : 0.f;

    __shared__ float sred[8];
    if (sub == 0) sred[threadIdx.x >> 5] = local;
    __syncthreads();
    if (threadIdx.x == 0) {
        float s = 0.f;
        #pragma unroll
        for (int i = 0; i < 8; ++i) s += sred[i];
        ws[blockIdx.x] = s;
    }
}

__launch_bounds__(1024)
__global__ void hybrid_pass2(const float* __restrict__ ws,
                             float* __restrict__ out, int n) {
    float s = 0.f;
    for (int i = threadIdx.x; i < n; i += 1024) s += ws[i];
    #pragma unroll
    for (int off = 32; off > 0; off >>= 1) s += __shfl_xor(s, off, 64);
    __shared__ float sm[16];
    if ((threadIdx.x & 63) == 0) sm[threadIdx.x >> 6] = s;
    __syncthreads();
    if (threadIdx.x == 0) {
        float t = 0.f;
        #pragma unroll
        for (int i = 0; i < 16; ++i) t += sm[i];
        out[0] = t;
    }
}

extern "C" void kernel_launch(void* const* d_in, const int* in_sizes, int n_in,
                              void* d_out, int out_size, void* d_ws, size_t ws_size,
                              hipStream_t stream) {
    const float* assign     = (const float*)d_in[0];
    const float* cat        = (const float*)d_in[1];
    const float* assign_lab = (const float*)d_in[2];
    const float* cat_lab    = (const float*)d_in[3];
    float* out = (float*)d_out;
    float* ws  = (float*)d_ws;

    const int B = in_sizes[0] / 300;       // T*J*J = 300

    // 4 b's per 32-lane half-wave; 8 halves per 256-thread block
    const int ITERS  = 4;
    const int halves = (B + ITERS - 1) / ITERS;
    const int blocks = (halves + 7) / 8;

    hybrid_pass1<<<blocks, 256, 0, stream>>>(assign, cat, assign_lab,
                                             cat_lab, ws, B);
    hybrid_pass2<<<1, 1024, 0, stream>>>(ws, out, blocks);
}